// Round 2
// 376.783 us; speedup vs baseline: 1.0098x; 1.0098x over previous
//
#include <hip/hip_runtime.h>

#define NN 8192
#define RPB 16                 // rows per block
#define NBLK (NN / RPB)        // 512 blocks
#define SLICE1 16              // slices summed per reduce1 block
#define SLICE2 32              // second-stage slice count

// native clang vector type: required by __builtin_nontemporal_load
typedef float vf4 __attribute__((ext_vector_type(4)));

// ws layout (floats): wv[NN] | diag[NN] | partial[NBLK*NN] | partial2[SLICE2*NN]

// Single-pass kernel: block b streams rows [16b, 16b+16) cooperatively, one
// row at a time. Each thread holds its 32 columns of the row in registers
// (8 vf4, non-temporal: ts is strictly streaming — keep L2/L3 for the
// partial buffer). The block reduces the sum of squares via shuffles + LDS,
// then ALL threads redundantly compute w_r = min(d/(rs-d),1)*V_r from the
// LDS broadcast — no serialized thread-0 section and only ONE barrier per
// row (red[] is parity double-buffered so row r+1's writes can't clobber
// row r's reads). diag and V loads for the next row are issued with the
// prefetch so their latency hides under the current row's reduce.
__global__ void __launch_bounds__(256)
main_pass(const float* __restrict__ ts,
          const float* __restrict__ state,
          float* __restrict__ wv,
          float* __restrict__ diag,
          float* __restrict__ partial)
{
    __shared__ float red[2][4];

    const int tid  = threadIdx.x;
    const int lane = tid & 63;
    const int wid  = tid >> 6;
    const int row0 = blockIdx.x * RPB;

    vf4 acc[8];
    #pragma unroll
    for (int k = 0; k < 8; ++k) acc[k] = (vf4)(0.f);

    vf4 cur[8], nxt[8];
    {
        const vf4* rp = (const vf4*)(ts + (size_t)row0 * NN);
        #pragma unroll
        for (int k = 0; k < 8; ++k)
            cur[k] = __builtin_nontemporal_load(rp + tid + k * 256);
    }
    float dcur = ts[(size_t)row0 * NN + row0];   // broadcast load (same addr all lanes)
    float vcur = state[3 * row0 + 2];

    #pragma unroll
    for (int r = 0; r < RPB; ++r) {
        const int row = row0 + r;
        float dnxt = 0.f, vnxt = 0.f;
        if (r + 1 < RPB) {                 // prefetch next row before the barrier
            const vf4* np = (const vf4*)(ts + (size_t)(row + 1) * NN);
            #pragma unroll
            for (int k = 0; k < 8; ++k)
                nxt[k] = __builtin_nontemporal_load(np + tid + k * 256);
            dnxt = ts[(size_t)(row + 1) * NN + (row + 1)];
            vnxt = state[3 * (row + 1) + 2];
        }
        // partial sum of squares over this thread's 32 columns
        float s = 0.f;
        #pragma unroll
        for (int k = 0; k < 8; ++k) {
            vf4 v = cur[k];
            s += v.x * v.x + v.y * v.y + v.z * v.z + v.w * v.w;
        }
        #pragma unroll
        for (int off = 32; off; off >>= 1) s += __shfl_down(s, off);
        if (lane == 0) red[r & 1][wid] = s;
        __syncthreads();
        // all threads compute the row scalars redundantly (LDS broadcast reads)
        const float total = red[r & 1][0] + red[r & 1][1]
                          + red[r & 1][2] + red[r & 1][3];
        const float d  = dcur * dcur;
        const float wr = fminf(d / (total - d), 1.0f) * vcur;
        if (tid == 0) { wv[row] = wr; diag[row] = d; }
        #pragma unroll
        for (int k = 0; k < 8; ++k) {       // weighted accumulate from registers
            vf4 v = cur[k];
            acc[k].x += wr * v.x * v.x;
            acc[k].y += wr * v.y * v.y;
            acc[k].z += wr * v.z * v.z;
            acc[k].w += wr * v.w * v.w;
        }
        if (r + 1 < RPB) {
            #pragma unroll
            for (int k = 0; k < 8; ++k) cur[k] = nxt[k];
            dcur = dnxt;
            vcur = vnxt;
        }
    }
    // write the block's partial slice (32 KB, coalesced float4, cached:
    // reduce1 re-reads it shortly)
    vf4* po = (vf4*)(partial + (size_t)blockIdx.x * NN);
    #pragma unroll
    for (int k = 0; k < 8; ++k) po[tid + k * 256] = acc[k];
}

// Reduce 512 slices -> 32 slices. grid(8, 32): x = col group (1024 cols),
// y = slice group (sums 16 slices). float4 coalesced; source is L3-hot
// (ts was streamed non-temporally, so partial should have survived).
__global__ void __launch_bounds__(256)
reduce1(const float* __restrict__ partial, float* __restrict__ partial2)
{
    const int col = blockIdx.x * 1024 + threadIdx.x * 4;
    const float* base = partial + (size_t)blockIdx.y * SLICE1 * NN + col;
    vf4 acc = (vf4)(0.f);
    #pragma unroll
    for (int k = 0; k < SLICE1; ++k) {
        vf4 v = *(const vf4*)(base + (size_t)k * NN);
        acc += v;
    }
    *(vf4*)(partial2 + (size_t)blockIdx.y * NN + col) = acc;
}

// Reduce 32 slices + all O(N) elementwise math.
__global__ void __launch_bounds__(256)
finalize(const float* __restrict__ state,
         const float* __restrict__ betas,
         const float* __restrict__ deltas,
         const float* __restrict__ cs,
         const float* __restrict__ ps,
         const float* __restrict__ wv,
         const float* __restrict__ diag,
         const float* __restrict__ partial2,
         float* __restrict__ out)
{
    const int j = blockIdx.x * 256 + threadIdx.x;
    float coup = 0.f;
    #pragma unroll 8
    for (int k = 0; k < SLICE2; ++k) coup += partial2[(size_t)k * NN + j];
    const float dj = diag[j];
    coup -= wv[j] * dj;                                // remove i==j term

    const float U = state[3 * j + 0];
    const float I = state[3 * j + 1];
    const float V = state[3 * j + 2];
    const float b2 = betas[j] * betas[j];
    const float d2 = deltas[j] * deltas[j];
    const float p2 = ps[j] * ps[j];
    const float c2 = cs[j] * cs[j];
    const float bUV = b2 * U * V;

    out[3 * j + 0] = -bUV;
    out[3 * j + 1] = bUV - d2 * I;
    out[3 * j + 2] = p2 * I - c2 * V - dj + coup;
}

extern "C" void kernel_launch(void* const* d_in, const int* in_sizes, int n_in,
                              void* d_out, int out_size, void* d_ws, size_t ws_size,
                              hipStream_t stream) {
    // inputs: 0:t 1:state 2:betas 3:deltas 4:cs 5:ps 6:ts
    const float* state  = (const float*)d_in[1];
    const float* betas  = (const float*)d_in[2];
    const float* deltas = (const float*)d_in[3];
    const float* cs     = (const float*)d_in[4];
    const float* ps     = (const float*)d_in[5];
    const float* ts     = (const float*)d_in[6];
    float* out = (float*)d_out;

    float* wv       = (float*)d_ws;
    float* diag     = wv + NN;
    float* partial  = diag + NN;
    float* partial2 = partial + (size_t)NBLK * NN;

    main_pass<<<NBLK, 256, 0, stream>>>(ts, state, wv, diag, partial);
    reduce1<<<dim3(8, SLICE2), 256, 0, stream>>>(partial, partial2);
    finalize<<<NN / 256, 256, 0, stream>>>(state, betas, deltas, cs, ps,
                                           wv, diag, partial2, out);
}

// Round 6
// 374.136 us; speedup vs baseline: 1.0170x; 1.0071x over previous
//
#include <hip/hip_runtime.h>

#define NN 8192
#define RPB 16                 // rows per block
#define NBLK (NN / RPB)        // 512 blocks
#define SLICEG 64              // slices summed per thread-group in reduce_finalize

// native clang vector type: required by __builtin_nontemporal_load
typedef float vf4 __attribute__((ext_vector_type(4)));

// ws layout (floats): wv[NN] | diag[NN] | partial[NBLK*NN]

// Single-pass kernel (verified R2 structure): block b streams rows
// [16b, 16b+16) cooperatively, one row at a time. Each thread holds its 32
// columns in registers (8 vf4, non-temporal: ts is strictly streaming).
// Block reduces sum-of-squares (shuffle + LDS, parity double-buffered so
// ONE barrier per row), all threads redundantly compute
// w_r = min(d/(rs-d),1)*V_r, FMA into per-thread column accumulators.
// ts is read from HBM exactly once; next-row prefetch + diag/V loads are
// issued before the barrier so their latency overlaps the reduce.
__global__ void __launch_bounds__(256)
main_pass(const float* __restrict__ ts,
          const float* __restrict__ state,
          float* __restrict__ wv,
          float* __restrict__ diag,
          float* __restrict__ partial)
{
    __shared__ float red[2][4];

    const int tid  = threadIdx.x;
    const int lane = tid & 63;
    const int wid  = tid >> 6;
    const int row0 = blockIdx.x * RPB;

    vf4 acc[8];
    #pragma unroll
    for (int k = 0; k < 8; ++k) acc[k] = (vf4)(0.f);

    vf4 cur[8], nxt[8];
    {
        const vf4* rp = (const vf4*)(ts + (size_t)row0 * NN);
        #pragma unroll
        for (int k = 0; k < 8; ++k)
            cur[k] = __builtin_nontemporal_load(rp + tid + k * 256);
    }
    float dcur = ts[(size_t)row0 * NN + row0];   // broadcast load
    float vcur = state[3 * row0 + 2];

    #pragma unroll
    for (int r = 0; r < RPB; ++r) {
        const int row = row0 + r;
        float dnxt = 0.f, vnxt = 0.f;
        if (r + 1 < RPB) {                 // prefetch next row before the barrier
            const vf4* np = (const vf4*)(ts + (size_t)(row + 1) * NN);
            #pragma unroll
            for (int k = 0; k < 8; ++k)
                nxt[k] = __builtin_nontemporal_load(np + tid + k * 256);
            dnxt = ts[(size_t)(row + 1) * NN + (row + 1)];
            vnxt = state[3 * (row + 1) + 2];
        }
        // partial sum of squares over this thread's 32 columns
        float s = 0.f;
        #pragma unroll
        for (int k = 0; k < 8; ++k) {
            vf4 v = cur[k];
            s += v.x * v.x + v.y * v.y + v.z * v.z + v.w * v.w;
        }
        #pragma unroll
        for (int off = 32; off; off >>= 1) s += __shfl_down(s, off);
        if (lane == 0) red[r & 1][wid] = s;
        __syncthreads();
        // all threads compute the row scalars redundantly (LDS broadcasts)
        const float total = red[r & 1][0] + red[r & 1][1]
                          + red[r & 1][2] + red[r & 1][3];
        const float d  = dcur * dcur;
        const float wr = fminf(d / (total - d), 1.0f) * vcur;
        if (tid == 0) { wv[row] = wr; diag[row] = d; }
        #pragma unroll
        for (int k = 0; k < 8; ++k) {       // weighted accumulate from registers
            vf4 v = cur[k];
            acc[k].x += wr * v.x * v.x;
            acc[k].y += wr * v.y * v.y;
            acc[k].z += wr * v.z * v.z;
            acc[k].w += wr * v.w * v.w;
        }
        if (r + 1 < RPB) {
            #pragma unroll
            for (int k = 0; k < 8; ++k) cur[k] = nxt[k];
            dcur = dnxt;
            vcur = vnxt;
        }
    }
    // write the block's partial slice (32 KB, coalesced float4)
    vf4* po = (vf4*)(partial + (size_t)blockIdx.x * NN);
    #pragma unroll
    for (int k = 0; k < 8; ++k) po[tid + k * 256] = acc[k];
}

// Fused reduce + finalize. 256 blocks x 256 threads. Block b owns 32
// columns [32b, 32b+32); thread (g = tid>>5, c = tid&31) sums 64 of the
// 512 slices for column 32b+c (each wave-load touches 2 x 128 B segments),
// LDS-reduce the 8 groups, then 32 threads do the O(N) elementwise math.
__global__ void __launch_bounds__(256)
reduce_finalize(const float* __restrict__ state,
                const float* __restrict__ betas,
                const float* __restrict__ deltas,
                const float* __restrict__ cs,
                const float* __restrict__ ps,
                const float* __restrict__ wv,
                const float* __restrict__ diag,
                const float* __restrict__ partial,
                float* __restrict__ out)
{
    __shared__ float redsum[8][32];
    const int tid = threadIdx.x;
    const int c   = tid & 31;
    const int g   = tid >> 5;
    const int j0  = blockIdx.x * 32;

    const float* base = partial + (size_t)g * SLICEG * NN + j0 + c;
    float s = 0.f;
    #pragma unroll 8
    for (int i = 0; i < SLICEG; ++i)
        s += base[(size_t)i * NN];
    redsum[g][c] = s;
    __syncthreads();

    if (tid < 32) {
        const int j = j0 + tid;
        float coup = 0.f;
        #pragma unroll
        for (int w = 0; w < 8; ++w) coup += redsum[w][tid];
        const float dj = diag[j];
        coup -= wv[j] * dj;                            // remove i==j term

        const float U = state[3 * j + 0];
        const float I = state[3 * j + 1];
        const float V = state[3 * j + 2];
        const float b2 = betas[j] * betas[j];
        const float d2 = deltas[j] * deltas[j];
        const float p2 = ps[j] * ps[j];
        const float c2 = cs[j] * cs[j];
        const float bUV = b2 * U * V;

        out[3 * j + 0] = -bUV;
        out[3 * j + 1] = bUV - d2 * I;
        out[3 * j + 2] = p2 * I - c2 * V - dj + coup;
    }
}

extern "C" void kernel_launch(void* const* d_in, const int* in_sizes, int n_in,
                              void* d_out, int out_size, void* d_ws, size_t ws_size,
                              hipStream_t stream) {
    // inputs: 0:t 1:state 2:betas 3:deltas 4:cs 5:ps 6:ts
    const float* state  = (const float*)d_in[1];
    const float* betas  = (const float*)d_in[2];
    const float* deltas = (const float*)d_in[3];
    const float* cs     = (const float*)d_in[4];
    const float* ps     = (const float*)d_in[5];
    const float* ts     = (const float*)d_in[6];
    float* out = (float*)d_out;

    float* wv       = (float*)d_ws;
    float* diag     = wv + NN;
    float* partial  = diag + NN;

    main_pass<<<NBLK, 256, 0, stream>>>(ts, state, wv, diag, partial);
    reduce_finalize<<<NN / 32, 256, 0, stream>>>(state, betas, deltas, cs, ps,
                                                 wv, diag, partial, out);
}